// Round 1
// baseline (166.219 us; speedup 1.0000x reference)
//
#include <hip/hip_runtime.h>
#include <math.h>

#define NS 24

typedef float v2f __attribute__((ext_vector_type(2)));
typedef float v4f __attribute__((ext_vector_type(4)));

// ws layout (SoA): float partials[5][B] rows = {sp2, st2, spt, mp, mt}

// 256-entry pixel table: entries 0..194 = circle Voronoi px, 195 = padding px
// (16,24) with label 0, 196..255 = dump entries pointing at the unread xi=17
// column (writes race benignly; nothing reads them). Encoded (yy<<8)|x, yy=y-8.
struct PixTab { unsigned short v[256]; };
__device__ constexpr PixTab make_pix() {
    PixTab t{};
    int n = 0;
    const int w[16] = {0,3,5,6,6,7,7,7,8,7,7,7,6,6,5,3};
    for (int yy = 0; yy < 16; ++yy)
        for (int x = 16 - w[yy]; x <= 16 + w[yy]; ++x)
            if (x < 24) { t.v[n] = (unsigned short)((yy << 8) | x); n = n + 1; }
    t.v[195] = (unsigned short)((8 << 8) | 24);
    for (int e = 196; e < 256; ++e)
        t.v[e] = (unsigned short)(((e & 15) << 8) | 25);   // xi=17 dump slots
    return t;
}
__device__ constexpr PixTab PIX = make_pix();

// ---- compile-time twiddle tables (copied to LDS per block; exact 32nd roots) ----
constexpr float twc_(int p) {
    const float C[17] = {
        1.0f, 0.98078528040323044913f, 0.92387953251128675613f, 0.83146961230254523708f,
        0.70710678118654752440f, 0.55557023301960222474f, 0.38268343236508977173f,
        0.19509032201612826785f, 0.0f,
        -0.19509032201612826785f, -0.38268343236508977173f, -0.55557023301960222474f,
        -0.70710678118654752440f, -0.83146961230254523708f, -0.92387953251128675613f,
        -0.98078528040323044913f, -1.0f };
    return (p <= 16) ? C[p] : C[32 - p];
}
constexpr float tws_(int p) {
    const float S[17] = {
        0.0f, 0.19509032201612826785f, 0.38268343236508977173f, 0.55557023301960222474f,
        0.70710678118654752440f, 0.83146961230254523708f, 0.92387953251128675613f,
        0.98078528040323044913f, 1.0f,
        0.98078528040323044913f, 0.92387953251128675613f, 0.83146961230254523708f,
        0.70710678118654752440f, 0.55557023301960222474f, 0.38268343236508977173f,
        0.19509032201612826785f, 0.0f };
    return (p <= 16) ? -S[p] : S[32 - p];
}
// TW1G[l0][xi] = e^{-2pi i l0 (xi+8)/32}, l0 in [0,8), xi in [0,17), stride 18 cplx
struct alignas(16) TW1T { float v[8 * 18 * 2]; };
__device__ constexpr TW1T make_tw1() {
    TW1T t{};
    for (int l0 = 0; l0 < 8; ++l0)
        for (int xi = 0; xi < 17; ++xi) {
            int p = (l0 * (xi + 8)) & 31;
            t.v[(l0 * 18 + xi) * 2 + 0] = twc_(p);
            t.v[(l0 * 18 + xi) * 2 + 1] = tws_(p);
        }
    return t;
}
__device__ constexpr TW1T TW1G = make_tw1();
// TW2G[k0][yp] = e^{-2pi i k0 (yp+8)/32}, k0 in [0,4), yp in [0,16), stride 18 cplx
struct alignas(16) TW2T { float v[4 * 18 * 2]; };
__device__ constexpr TW2T make_tw2() {
    TW2T t{};
    for (int k0 = 0; k0 < 4; ++k0)
        for (int yp = 0; yp < 16; ++yp) {
            int p = (k0 * (yp + 8)) & 31;
            t.v[(k0 * 18 + yp) * 2 + 0] = twc_(p);
            t.v[(k0 * 18 + yp) * 2 + 1] = tws_(p);
        }
    return t;
}
__device__ constexpr TW2T TW2G = make_tw2();

// packed complex mul with w = (c, s)
static __device__ __forceinline__ v2f cmul(v2f e, v2f w) {
    v2f m = (v2f){e.y, e.y} * (v2f){w.y, w.x};
    return __builtin_elementwise_fma((v2f){e.x, e.x}, w, (v2f){-m.x, m.y});
}
static __device__ __forceinline__ float mag(v2f h) {
    v2f q = h * h;
    return sqrtf(q.x + q.y);
}

// DPP wave reduce (VALU pipe). dpp_ctrl must be a constant -> template param.
template <int CTRL>
static __device__ __forceinline__ float dpp_step(float x) {
    int y = __builtin_amdgcn_update_dpp(0, __float_as_int(x), CTRL, 0xf, 0xf, true);
    return __int_as_float(y);
}
static __device__ __forceinline__ float wave_sum(float x) {
    x += dpp_step<0x111>(x);  // row_shr:1
    x += dpp_step<0x112>(x);  // row_shr:2
    x += dpp_step<0x114>(x);  // row_shr:4
    x += dpp_step<0x118>(x);  // row_shr:8
    x += dpp_step<0x142>(x);  // row_bcast:15
    x += dpp_step<0x143>(x);  // row_bcast:31
    return x;                 // lane 63 holds the wave total
}
static __device__ __forceinline__ float wave_max(float x) {
    x = fmaxf(x, dpp_step<0x111>(x));
    x = fmaxf(x, dpp_step<0x112>(x));
    x = fmaxf(x, dpp_step<0x114>(x));
    x = fmaxf(x, dpp_step<0x118>(x));
    x = fmaxf(x, dpp_step<0x142>(x));
    x = fmaxf(x, dpp_step<0x143>(x));
    return x;
}

// ============================================================================
// One WAVE per batch; 4 batches per 256-thread block; ZERO __syncthreads.
// All inter-phase dataflow is wave-local LDS (DS pipe is in-order per wave;
// wave_barrier() pins compiler ordering at phase boundaries, emits nothing).
// LDS per wave: R1 (5120 B): gx -> e2f -> pmf ; R2 (4608 B): gyT -> gT2f.
// Shared per block: tw1 (1152 B) + tw2 (576 B). Total 1728 + 4*9728 = 40640 B
// -> exactly 4 blocks/CU (16 waves/CU).
// ============================================================================
__global__ __launch_bounds__(256, 4)
void loss_main(const float* __restrict__ output, const float* __restrict__ targets,
               float* __restrict__ partials, int Btot) {
    __shared__ __align__(16) char lds_all[40640];
    float* tw1f = (float*)lds_all;                  // [0, 1152)
    float* tw2f = (float*)(lds_all + 1152);         // [1152, 1728)
    const int t = threadIdx.x;
    const int lane = t & 63;
    const int w = __builtin_amdgcn_readfirstlane(t >> 6);
    char* wbase = lds_all + 1728 + w * 9728;
    float* R1 = (float*)wbase;                      // 5120 B
    float* R2 = (float*)(wbase + 5120);             // 4608 B
    const int batch = blockIdx.x * 4 + w;
    if (batch >= Btot) return;                      // wave-uniform; no barriers anywhere
    const float* so = output + batch * (NS * 3);    // wave-uniform seeds (scalar loads)
    const float* tg = targets + batch * (NS * 3);
    const float TP = 6.2831853071795864f;

    // ---- twiddle copy: every wave copies the shared tables redundantly
    // (identical values; each wave's reads are ordered after its own writes) ----
    {
        int i0 = lane;
        *(v4f*)&tw1f[i0 * 4] = *(const v4f*)&TW1G.v[i0 * 4];
        int i1 = lane + 64;
        if (i1 < 72)       *(v4f*)&tw1f[i1 * 4] = *(const v4f*)&TW1G.v[i1 * 4];
        else if (i1 < 108) *(v4f*)&tw2f[(i1 - 72) * 4] = *(const v4f*)&TW2G.v[(i1 - 72) * 4];
    }

    // ---- gaussian tables (amp folded into gx) ----
    float* gx  = R1;        // [24][32]
    float* gyT = R2;        // [32 rows][24 s], stride 28 (16B-aligned, ~2-way banks)
#pragma unroll
    for (int k = 0; k < 12; ++k) {
        int idx = lane + 64 * k;            // 768 = 24 s x 32 c
        int s = idx >> 5, c = idx & 31;
        float dx = (float)c - tg[3 * s];
        gx[idx] = tg[3 * s + 2] * __expf(dx * dx * (-1.0f / 4.5f));
    }
#pragma unroll
    for (int k = 0; k < 12; ++k) {
        int idx = lane + 64 * k;            // 768 = 32 r x 24 s
        int r = idx / 24, s = idx - r * 24;
        float dy = (float)r - tg[3 * s + 1];
        gyT[r * 28 + s] = __expf(dy * dy * (-1.0f / 4.5f));
    }
    __builtin_amdgcn_wave_barrier();

    // ---- target-gen into registers: rows rr, rr+16; cols cc0..cc0+7 ----
    const int rr = lane >> 2;
    const int cc0 = (lane & 3) * 8;
    v2f ta0 = {0,0}, ta1 = {0,0}, ta2 = {0,0}, ta3 = {0,0};
    v2f tb0 = {0,0}, tb1 = {0,0}, tb2 = {0,0}, tb3 = {0,0};
#pragma unroll
    for (int q = 0; q < 6; ++q) {
        v4f gy4a = *(const v4f*)&gyT[rr * 28 + q * 4];
        v4f gy4b = *(const v4f*)&gyT[(rr + 16) * 28 + q * 4];
#pragma unroll
        for (int j = 0; j < 4; ++j) {
            v4f glo = *(const v4f*)&gx[(4 * q + j) * 32 + cc0];
            v4f ghi = *(const v4f*)&gx[(4 * q + j) * 32 + cc0 + 4];
            float ga = (j == 0) ? gy4a.x : (j == 1) ? gy4a.y : (j == 2) ? gy4a.z : gy4a.w;
            float gb = (j == 0) ? gy4b.x : (j == 1) ? gy4b.y : (j == 2) ? gy4b.z : gy4b.w;
            v2f g01 = {glo.x, glo.y}, g23 = {glo.z, glo.w};
            v2f g45 = {ghi.x, ghi.y}, g67 = {ghi.z, ghi.w};
            ta0 = __builtin_elementwise_fma((v2f){ga, ga}, g01, ta0);
            ta1 = __builtin_elementwise_fma((v2f){ga, ga}, g23, ta1);
            ta2 = __builtin_elementwise_fma((v2f){ga, ga}, g45, ta2);
            ta3 = __builtin_elementwise_fma((v2f){ga, ga}, g67, ta3);
            tb0 = __builtin_elementwise_fma((v2f){gb, gb}, g01, tb0);
            tb1 = __builtin_elementwise_fma((v2f){gb, gb}, g23, tb1);
            tb2 = __builtin_elementwise_fma((v2f){gb, gb}, g45, tb2);
            tb3 = __builtin_elementwise_fma((v2f){gb, gb}, g67, tb3);
        }
    }
    __builtin_amdgcn_wave_barrier();

    // ---- zero e2f region (overwrites gx -- dead after target-gen) ----
    float* e2f = R1;        // [16][18] cplx, stride 18 cplx
#pragma unroll
    for (int o = 0; o < 3; ++o) {
        int idx = lane + 64 * o;
        if (idx < 144) *(v4f*)&e2f[idx * 4] = (v4f){0.f, 0.f, 0.f, 0.f};
    }

    // ---- Voronoi: 4 px/lane (2 packed pairs), single pass over 24 seeds ----
    {
        unsigned ppA = *(const unsigned*)&PIX.v[2 * lane];
        unsigned ppB = *(const unsigned*)&PIX.v[2 * lane + 128];
        int pvA0 = (int)(ppA & 0xffffu), pvA1 = (int)(ppA >> 16);
        int pvB0 = (int)(ppB & 0xffffu), pvB1 = (int)(ppB >> 16);
        int yA0 = pvA0 >> 8, xA0 = (pvA0 & 255) - 8;
        int yA1 = pvA1 >> 8, xA1 = (pvA1 & 255) - 8;
        int yB0 = pvB0 >> 8, xB0 = (pvB0 & 255) - 8;
        int yB1 = pvB1 >> 8, xB1 = (pvB1 & 255) - 8;
        v2f FIA = {(float)yA0, (float)yA1}, FJA = {(float)xA0, (float)xA1};
        v2f FIB = {(float)yB0, (float)yB1}, FJB = {(float)xB0, (float)xB1};
        v2f bdA = {1e30f, 1e30f}, bphA = {0.f, 0.f};
        v2f bdB = {1e30f, 1e30f}, bphB = {0.f, 0.f};
#pragma unroll
        for (int s = 0; s < NS; ++s) {
            float sx = so[3 * s], sy = so[3 * s + 1], phs = so[3 * s + 2];
            v2f dXA = FIA - (v2f){sx, sx};
            v2f dYA = FJA - (v2f){sy, sy};
            v2f d2A = __builtin_elementwise_fma(dXA, dXA, dYA * dYA);
            v2f dXB = FIB - (v2f){sx, sx};
            v2f dYB = FJB - (v2f){sy, sy};
            v2f d2B = __builtin_elementwise_fma(dXB, dXB, dYB * dYB);
            if (d2A.x < bdA.x) { bdA.x = d2A.x; bphA.x = phs; }  // strict <: first-min tie
            if (d2A.y < bdA.y) { bdA.y = d2A.y; bphA.y = phs; }
            if (d2B.x < bdB.x) { bdB.x = d2B.x; bphB.x = phs; }
            if (d2B.y < bdB.y) { bdB.y = d2B.y; bphB.y = phs; }
        }
        // pixel 195 = padding (16,24): label 0 -> phase so[2]
        float phB1 = (2 * lane + 129 == 195) ? so[2] : bphB.y;
        float svA0, cvA0, svA1, cvA1, svB0, cvB0, svB1, cvB1;
        __sincosf(TP * bphA.x, &svA0, &cvA0);
        __sincosf(TP * bphA.y, &svA1, &cvA1);
        __sincosf(TP * bphB.x, &svB0, &cvB0);
        __sincosf(TP * phB1,   &svB1, &cvB1);
        *(v2f*)&e2f[(yA0 * 18 + xA0) * 2] = (v2f){cvA0 - 1.0f, svA0};
        *(v2f*)&e2f[(yA1 * 18 + xA1) * 2] = (v2f){cvA1 - 1.0f, svA1};
        *(v2f*)&e2f[(yB0 * 18 + xB0) * 2] = (v2f){cvB0 - 1.0f, svB0};
        *(v2f*)&e2f[(yB1 * 18 + xB1) * 2] = (v2f){cvB1 - 1.0f, svB1};
    }
    __builtin_amdgcn_wave_barrier();

    // ---- stage 1: radix-4 row DFT over x=8..24; 2 tasks/lane, 4 outputs each ----
    float* gT2f = R2;       // overlays gyT (dead); [32 l][16 yp] cplx, stride 18 cplx
#pragma unroll
    for (int h = 0; h < 2; ++h) {
        const int tau = lane + 64 * h;
        const int yy = tau >> 3, l0 = tau & 7;
        const float* row = &e2f[yy * 36];
        const float* twr = &tw1f[l0 * 36];
        v2f c0 = {0,0}, c1 = {0,0}, c2 = {0,0}, c3 = {0,0};
#pragma unroll
        for (int q = 0; q < 8; ++q) {
            v4f e4 = *(const v4f*)&row[q * 4];   // cplx xi=2q, 2q+1
            v4f w4 = *(const v4f*)&twr[q * 4];
            v2f ca = cmul((v2f){e4.x, e4.y}, (v2f){w4.x, w4.y});
            v2f cb = cmul((v2f){e4.z, e4.w}, (v2f){w4.z, w4.w});
            if ((q & 1) == 0) { c0 += ca; c1 += cb; }
            else              { c2 += ca; c3 += cb; }
        }
        {   // tail xi=16 (x=24), m=0
            v2f e16 = *(const v2f*)&row[32];
            v2f w16 = *(const v2f*)&twr[32];
            c0 += cmul(e16, w16);
        }
        v2f a = c0 + c2, bb = c0 - c2;
        v2f cc = c1 + c3, d = c1 - c3;
        v2f du = {d.y, -d.x};   // -i * d
        *(v2f*)&gT2f[l0 * 36 + yy * 2]        = a + cc;
        *(v2f*)&gT2f[(l0 + 8) * 36 + yy * 2]  = bb + du;
        *(v2f*)&gT2f[(l0 + 16) * 36 + yy * 2] = a - cc;
        *(v2f*)&gT2f[(l0 + 24) * 36 + yy * 2] = bb - du;
    }
    __builtin_amdgcn_wave_barrier();

    // ---- stage 2: radix-8 col DFT + |.|; 2 tasks/lane, 8 outputs each ----
    float sv24, cv24;
    __sincosf(TP * so[2], &sv24, &cv24);
    const float e24x = cv24 - 1.0f, e24y = sv24;
    float* pmf = R1;        // overlays e2f (dead); |pred| fftshifted, stride 40
#pragma unroll
    for (int h = 0; h < 2; ++h) {
        const int tau = lane + 64 * h;
        const int l = tau >> 2, k0 = tau & 3;
        const float* gTr = &gT2f[l * 36];
        const float* twr = &tw2f[k0 * 36];
        v2f c[8];
#pragma unroll
        for (int q = 0; q < 4; ++q) {
            v4f glo = *(const v4f*)&gTr[q * 4];        // yp = 2q, 2q+1
            v4f ghi = *(const v4f*)&gTr[q * 4 + 16];   // yp = 2q+8, 2q+9
            v4f wlo = *(const v4f*)&twr[q * 4];
            v4f whi = *(const v4f*)&twr[q * 4 + 16];
            c[2 * q]     = cmul((v2f){glo.x, glo.y}, (v2f){wlo.x, wlo.y})
                         + cmul((v2f){ghi.x, ghi.y}, (v2f){whi.x, whi.y});
            c[2 * q + 1] = cmul((v2f){glo.z, glo.w}, (v2f){wlo.z, wlo.w})
                         + cmul((v2f){ghi.z, ghi.w}, (v2f){whi.z, whi.w});
        }
        v2f Ea = c[0] + c[4], Eb = c[0] - c[4];
        v2f Ec = c[2] + c[6], Ed = c[2] - c[6];
        v2f Edu = {Ed.y, -Ed.x};
        v2f E0 = Ea + Ec, E1 = Eb + Edu, E2 = Ea - Ec, E3 = Eb - Edu;
        v2f Oa = c[1] + c[5], Ob = c[1] - c[5];
        v2f Oc = c[3] + c[7], Od = c[3] - c[7];
        v2f Odu = {Od.y, -Od.x};
        v2f O0 = Oa + Oc, O1 = Ob + Odu, O2 = Oa - Oc, O3 = Ob - Odu;
        const float s2c = 0.70710678118654752440f;
        v2f w1O = (v2f){s2c, s2c} * (v2f){O1.x + O1.y, O1.y - O1.x};     // w * O1
        v2f w3O = (v2f){s2c, s2c} * (v2f){O3.y - O3.x, -(O3.x + O3.y)};  // w^3 * O3
        v2f miO = {O2.y, -O2.x};                                         // -i * O2
        {   // analytic pixel (24,16): e24 * (-1)^l * i^k0 (same for all 8 j)
            float ar2 = (k0 == 0) ? 1.f : (k0 == 2) ? -1.f : 0.f;  // i^k0
            float ai2 = (k0 == 1) ? 1.f : (k0 == 3) ? -1.f : 0.f;
            float sgn = (l & 1) ? -1.f : 1.f;
            v2f T = {sgn * (e24x * ar2 - e24y * ai2),
                     sgn * (e24x * ai2 + e24y * ar2)};
            E0 += T; E1 += T; E2 += T; E3 += T;
        }
        v2f h0 = E0 + O0;
        if (tau == 0) h0.x += 1024.0f;   // FFT(ones) delta at (k,l)=(0,0)
        int v = (l + 16) & 31;
        pmf[(k0 + 16) * 40 + v] = mag(h0);          // k = k0
        pmf[(k0 + 20) * 40 + v] = mag(E1 + w1O);    // k = k0+4
        pmf[(k0 + 24) * 40 + v] = mag(E2 + miO);    // k = k0+8
        pmf[(k0 + 28) * 40 + v] = mag(E3 + w3O);    // k = k0+12
        pmf[(k0)      * 40 + v] = mag(E0 - O0);     // k = k0+16
        pmf[(k0 + 4)  * 40 + v] = mag(E1 - w1O);    // k = k0+20
        pmf[(k0 + 8)  * 40 + v] = mag(E2 - miO);    // k = k0+24
        pmf[(k0 + 12) * 40 + v] = mag(E3 - w3O);    // k = k0+28
    }
    __builtin_amdgcn_wave_barrier();

    // ---- tail: combine pmf with registered target values; 16 px/lane ----
    {
        v4f p4a = *(const v4f*)&pmf[rr * 40 + cc0];
        v4f p4b = *(const v4f*)&pmf[rr * 40 + cc0 + 4];
        v4f p4c = *(const v4f*)&pmf[(rr + 16) * 40 + cc0];
        v4f p4d = *(const v4f*)&pmf[(rr + 16) * 40 + cc0 + 4];
        v2f pa0 = {p4a.x, p4a.y}, pa1 = {p4a.z, p4a.w};
        v2f pa2 = {p4b.x, p4b.y}, pa3 = {p4b.z, p4b.w};
        v2f pb0 = {p4c.x, p4c.y}, pb1 = {p4c.z, p4c.w};
        v2f pb2 = {p4d.x, p4d.y}, pb3 = {p4d.z, p4d.w};
        v2f s2v = pa0 * pa0 + pa1 * pa1 + pa2 * pa2 + pa3 * pa3
                + pb0 * pb0 + pb1 * pb1 + pb2 * pb2 + pb3 * pb3;
        v2f t2v = ta0 * ta0 + ta1 * ta1 + ta2 * ta2 + ta3 * ta3
                + tb0 * tb0 + tb1 * tb1 + tb2 * tb2 + tb3 * tb3;
        v2f ptv = pa0 * ta0 + pa1 * ta1 + pa2 * ta2 + pa3 * ta3
                + pb0 * tb0 + pb1 * tb1 + pb2 * tb2 + pb3 * tb3;
        float sp2 = s2v.x + s2v.y;
        float st2 = t2v.x + t2v.y;
        float spt = ptv.x + ptv.y;
        v4f pmx = __builtin_elementwise_max(__builtin_elementwise_max(p4a, p4b),
                                            __builtin_elementwise_max(p4c, p4d));
        float mp = fmaxf(fmaxf(pmx.x, pmx.y), fmaxf(pmx.z, pmx.w));
        v2f tmx = __builtin_elementwise_max(__builtin_elementwise_max(ta0, ta1),
                                            __builtin_elementwise_max(ta2, ta3));
        tmx = __builtin_elementwise_max(tmx,
              __builtin_elementwise_max(__builtin_elementwise_max(tb0, tb1),
                                        __builtin_elementwise_max(tb2, tb3)));
        float mt = fmaxf(tmx.x, tmx.y);
        sp2 = wave_sum(sp2);
        st2 = wave_sum(st2);
        spt = wave_sum(spt);
        mp  = wave_max(mp);
        mt  = wave_max(mt);
        if (lane == 63) {
            partials[0 * Btot + batch] = sp2;
            partials[1 * Btot + batch] = st2;
            partials[2 * Btot + batch] = spt;
            partials[3 * Btot + batch] = mp;
            partials[4 * Btot + batch] = mt;
        }
    }
}

__global__ __launch_bounds__(1024)
void finalize_loss(const float* __restrict__ partials, float* __restrict__ out, int B) {
    __shared__ double reds[16][3];
    __shared__ float redx[16][2];
    const int t = threadIdx.x;
    double sp2 = 0.0, st2 = 0.0, spt = 0.0;
    float mp = 0.f, mt = 0.f;
    for (int i = t; i < B; i += 1024) {
        sp2 += (double)partials[0 * B + i];
        st2 += (double)partials[1 * B + i];
        spt += (double)partials[2 * B + i];
        mp = fmaxf(mp, partials[3 * B + i]);
        mt = fmaxf(mt, partials[4 * B + i]);
    }
    for (int off = 32; off > 0; off >>= 1) {
        sp2 += __shfl_down(sp2, off);
        st2 += __shfl_down(st2, off);
        spt += __shfl_down(spt, off);
        mp = fmaxf(mp, __shfl_down(mp, off));
        mt = fmaxf(mt, __shfl_down(mt, off));
    }
    int wave = t >> 6, lane = t & 63;
    if (lane == 0) {
        reds[wave][0] = sp2; reds[wave][1] = st2; reds[wave][2] = spt;
        redx[wave][0] = mp;  redx[wave][1] = mt;
    }
    __syncthreads();
    if (t == 0) {
        for (int w = 1; w < 16; ++w) {
            sp2 += reds[w][0];
            st2 += reds[w][1];
            spt += reds[w][2];
            mp = fmaxf(mp, redx[w][0]);
            mt = fmaxf(mt, redx[w][1]);
        }
        double Mp = (double)mp, Mt = (double)mt;
        double loss = (sp2 * (Mt / Mp) + st2 * (Mp / Mt) - 2.0 * spt) / sqrt(sp2 * st2);
        out[0] = (float)loss;
    }
}

extern "C" void kernel_launch(void* const* d_in, const int* in_sizes, int n_in,
                              void* d_out, int out_size, void* d_ws, size_t ws_size,
                              hipStream_t stream) {
    const float* output  = (const float*)d_in[0];
    const float* targets = (const float*)d_in[1];
    int B = in_sizes[0] / (NS * 3);
    float* partials = (float*)d_ws;     // 5*B floats

    int nb = (B + 3) >> 2;              // 4 batches (waves) per block
    loss_main<<<nb, 256, 0, stream>>>(output, targets, partials, B);
    finalize_loss<<<1, 1024, 0, stream>>>(partials, (float*)d_out, B);
}